// Round 2
// baseline (539.614 us; speedup 1.0000x reference)
//
#include <hip/hip_runtime.h>

typedef int v4i __attribute__((ext_vector_type(4)));

#define G_AS1 const __attribute__((address_space(1))) unsigned int
#define L_AS3 __attribute__((address_space(3))) unsigned int

// ---------------------------------------------------------------------------
// Per-row symmetric int8 fake-quant, ONE WAVE PER ROW (4 rows / 256-thr block).
// No LDS, no barriers: per-lane 16 float4 loads (64 elems), shuffle reduce.
// scale = max(|row|)/127 (IEEE div, clamp 1e-8); q = clip(rintf(v/scale)).
// ---------------------------------------------------------------------------
__global__ __launch_bounds__(256) void quant_rows_kernel(
    const float* __restrict__ in, signed char* __restrict__ q,
    float* __restrict__ scale, int ncols /*==4096*/)
{
    const int wid  = threadIdx.x >> 6;
    const int lane = threadIdx.x & 63;
    const int row  = (blockIdx.x << 2) + wid;   // nrows % 4 == 0 always here

    const float4* inr = (const float4*)(in + (size_t)row * ncols);

    float4 v[16];
    float amax = 0.0f;
#pragma unroll
    for (int i = 0; i < 16; ++i) {
        float4 t = inr[lane + (i << 6)];
        v[i] = t;
        amax = fmaxf(amax, fmaxf(fmaxf(fabsf(t.x), fabsf(t.y)),
                                 fmaxf(fabsf(t.z), fabsf(t.w))));
    }
#pragma unroll
    for (int off = 32; off; off >>= 1)
        amax = fmaxf(amax, __shfl_xor(amax, off));

    const float sc = fmaxf(amax / 127.0f, 1e-8f);   // IEEE div matches ref
    if (lane == 0) scale[row] = sc;

    int* qr = (int*)(q + (size_t)row * ncols);
#pragma unroll
    for (int i = 0; i < 16; ++i) {
        float4 t = v[i];
        int b0 = (int)fminf(fmaxf(rintf(t.x / sc), -127.0f), 127.0f);
        int b1 = (int)fminf(fmaxf(rintf(t.y / sc), -127.0f), 127.0f);
        int b2 = (int)fminf(fmaxf(rintf(t.z / sc), -127.0f), 127.0f);
        int b3 = (int)fminf(fmaxf(rintf(t.w / sc), -127.0f), 127.0f);
        qr[lane + (i << 6)] = (b0 & 255) | ((b1 & 255) << 8) |
                              ((b2 & 255) << 16) | (b3 << 24);
    }
}

// ---------------------------------------------------------------------------
// int8 GEMM, 128x128 tile, BK=64B, 4 waves (2x2), 4x4 16x16x64 frags/wave.
// Fragment-ordered LDS: tile = 16 rows x 64B = 1024B; lane slot l*16 holds
// A[row=l&15][kchunk=(l>>4)*16] -> ds_read_b128 at base+lane*16 = conflict-free.
// 2-phase double-buffer: STAGE(next) issued before compute(cur), ONE barrier
// per K-step (its implicit vmcnt(0) drain lands after compute hides latency).
// ---------------------------------------------------------------------------
__global__ __launch_bounds__(256) void gemm_i8_kernel(
    const signed char* __restrict__ A, const signed char* __restrict__ B,
    const float* __restrict__ sA, const float* __restrict__ sB,
    const float* __restrict__ bias, float* __restrict__ C,
    int M, int N, int K)
{
    // [2 buffers][8 tiles][1024 B] per operand
    __shared__ __attribute__((aligned(16))) signed char As[2 * 8192];
    __shared__ __attribute__((aligned(16))) signed char Bs[2 * 8192];

    const int tid = threadIdx.x;
    const int lane = tid & 63, wid = tid >> 6;
    const int wm = wid >> 1, wn = wid & 1;

    // XCD-aware bijective blockIdx swizzle (m204 form); nwg=2048 -> rr=0
    const int nwg = gridDim.x;
    const int xcd = blockIdx.x & 7, loc = blockIdx.x >> 3;
    const int qq = nwg >> 3, rr = nwg & 7;
    const int wg = (xcd < rr ? xcd * (qq + 1) : rr * (qq + 1) + (xcd - rr) * qq) + loc;

    const int nbn = N >> 7;
    const int m0 = (wg / nbn) << 7;
    const int n0 = (wg % nbn) << 7;

    // --- staging addresses (fragment order) ---
    // wave w stages A-tiles {2w,2w+1}, B-tiles {2w,2w+1}
    const int fr = lane & 15;            // row within 16-row tile
    const int fc = (lane >> 4) << 4;     // 16B k-chunk
    const signed char* gA = A + (size_t)(m0 + (wid << 5) + fr) * K + fc;
    const signed char* gB = B + (size_t)(n0 + (wid << 5) + fr) * K + fc;
    const size_t tstep = (size_t)16 * K; // tile 2w+1 = +16 rows

    // --- fragment read base: linear, conflict-free ---
    const signed char* pA0 = As + (wm << 12) + (lane << 4); // + fm*1024 (+ buf*8192)
    const signed char* pB0 = Bs + (wn << 12) + (lane << 4);

    v4i acc[4][4];
    const v4i vzero = {0, 0, 0, 0};
#pragma unroll
    for (int i = 0; i < 4; ++i)
#pragma unroll
        for (int j = 0; j < 4; ++j) acc[i][j] = vzero;

#define STAGE(buf, kt)                                                        \
    do {                                                                      \
        const signed char* ga = gA + (kt);                                    \
        const signed char* gb = gB + (kt);                                    \
        L_AS3* la = (L_AS3*)(As + (buf) * 8192 + (wid << 11));                \
        L_AS3* lb = (L_AS3*)(Bs + (buf) * 8192 + (wid << 11));                \
        __builtin_amdgcn_global_load_lds((G_AS1*)ga,           la,        16, 0, 0); \
        __builtin_amdgcn_global_load_lds((G_AS1*)(ga + tstep), la + 256,  16, 0, 0); \
        __builtin_amdgcn_global_load_lds((G_AS1*)gb,           lb,        16, 0, 0); \
        __builtin_amdgcn_global_load_lds((G_AS1*)(gb + tstep), lb + 256,  16, 0, 0); \
    } while (0)

    const int NT = K >> 6;   // 64 K-steps
    STAGE(0, 0);
    __syncthreads();         // implicit vmcnt(0) drain -> buf0 ready

    int cur = 0;
    for (int t = 0; t < NT; ++t) {
        if (t + 1 < NT) STAGE(cur ^ 1, (t + 1) << 6);

        const signed char* pa = pA0 + cur * 8192;
        const signed char* pb = pB0 + cur * 8192;
        v4i a[4], b[4];
#pragma unroll
        for (int f = 0; f < 4; ++f) {
            a[f] = *(const v4i*)(pa + (f << 10));
            b[f] = *(const v4i*)(pb + (f << 10));
        }
#pragma unroll
        for (int fm = 0; fm < 4; ++fm)
#pragma unroll
            for (int fn = 0; fn < 4; ++fn)
                acc[fm][fn] = __builtin_amdgcn_mfma_i32_16x16x64_i8(
                    a[fm], b[fn], acc[fm][fn], 0, 0, 0);

        __syncthreads();     // next buf ready + everyone done with cur
        cur ^= 1;
    }
#undef STAGE

    // epilogue: C/D layout col=lane&15, row=(lane>>4)*4+reg
    const int l15 = lane & 15;
    const int r4 = (lane >> 4) << 2;
#pragma unroll
    for (int fn = 0; fn < 4; ++fn) {
        const int col = n0 + (wn << 6) + (fn << 4) + l15;
        const float sb = sB[col];
        const float bv = bias[col];
#pragma unroll
        for (int fm = 0; fm < 4; ++fm) {
            const int rowb = m0 + (wm << 6) + (fm << 4) + r4;
#pragma unroll
            for (int r = 0; r < 4; ++r) {
                const int row = rowb + r;
                C[(size_t)row * N + col] =
                    (float)acc[fm][fn][r] * (sA[row] * sb) + bv;
            }
        }
    }
}

// ---------------------------------------------------------------------------
extern "C" void kernel_launch(void* const* d_in, const int* in_sizes, int n_in,
                              void* d_out, int out_size, void* d_ws, size_t ws_size,
                              hipStream_t stream) {
    const float* x    = (const float*)d_in[0];   // [M][K] fp32
    const float* w    = (const float*)d_in[1];   // [N][K] fp32
    const float* bias = (const float*)d_in[2];   // [N]
    float* out = (float*)d_out;

    const int N = in_sizes[2];            // 4096
    const int K = in_sizes[1] / N;        // 4096
    const int M = in_sizes[0] / K;        // 8192

    signed char* qx = (signed char*)d_ws;
    signed char* qw = qx + (size_t)M * K;
    float* sx = (float*)(qw + (size_t)N * K);
    float* sw = sx + M;

    quant_rows_kernel<<<M / 4, 256, 0, stream>>>(x, qx, sx, K);
    quant_rows_kernel<<<N / 4, 256, 0, stream>>>(w, qw, sw, K);

    dim3 grid((M / 128) * (N / 128));     // 2048 blocks
    gemm_i8_kernel<<<grid, 256, 0, stream>>>(qx, qw, sx, sw, bias, out, M, N, K);
}

// Round 3
// 396.399 us; speedup vs baseline: 1.3613x; 1.3613x over previous
//
#include <hip/hip_runtime.h>

typedef int v4i __attribute__((ext_vector_type(4)));

#define G_AS1 const __attribute__((address_space(1))) unsigned int
#define L_AS3 __attribute__((address_space(3))) unsigned int
typedef __attribute__((address_space(3))) signed char* lds_cp;

// inline-asm ds_read_b128 with literal offset (rule 18 discipline at use site)
#define DSR(d, a, OFF) \
    asm volatile("ds_read_b128 %0, %1 offset:" #OFF : "=v"(d) : "v"(a))

// ---------------------------------------------------------------------------
// Per-row symmetric int8 fake-quant, one wave per row (4 rows / block).
// scale = max(|row|)/127 (IEEE div, clamp 1e-8); q = clip(rintf(v/scale)).
// ---------------------------------------------------------------------------
__global__ __launch_bounds__(256) void quant_rows_kernel(
    const float* __restrict__ in, signed char* __restrict__ q,
    float* __restrict__ scale, int ncols /*==4096*/)
{
    const int wid  = threadIdx.x >> 6;
    const int lane = threadIdx.x & 63;
    const int row  = (blockIdx.x << 2) + wid;

    const float4* inr = (const float4*)(in + (size_t)row * ncols);

    float4 v[16];
    float amax = 0.0f;
#pragma unroll
    for (int i = 0; i < 16; ++i) {
        float4 t = inr[lane + (i << 6)];
        v[i] = t;
        amax = fmaxf(amax, fmaxf(fmaxf(fabsf(t.x), fabsf(t.y)),
                                 fmaxf(fabsf(t.z), fabsf(t.w))));
    }
#pragma unroll
    for (int off = 32; off; off >>= 1)
        amax = fmaxf(amax, __shfl_xor(amax, off));

    const float sc = fmaxf(amax / 127.0f, 1e-8f);
    if (lane == 0) scale[row] = sc;

    int* qr = (int*)(q + (size_t)row * ncols);
#pragma unroll
    for (int i = 0; i < 16; ++i) {
        float4 t = v[i];
        int b0 = (int)fminf(fmaxf(rintf(t.x / sc), -127.0f), 127.0f);
        int b1 = (int)fminf(fmaxf(rintf(t.y / sc), -127.0f), 127.0f);
        int b2 = (int)fminf(fmaxf(rintf(t.z / sc), -127.0f), 127.0f);
        int b3 = (int)fminf(fmaxf(rintf(t.w / sc), -127.0f), 127.0f);
        qr[lane + (i << 6)] = (b0 & 255) | ((b1 & 255) << 8) |
                              ((b2 & 255) << 16) | (b3 << 24);
    }
}

// ---------------------------------------------------------------------------
// int8 GEMM, 256x256 tile, BK=64, 8 waves (2Mx4N), wave tile 128x64.
// 3-buffer LDS ring (96KB), counted vmcnt(4) once per K-tile, 2 raw barriers
// per K-tile, 2 compute phases x 16 mfma_i32_16x16x64_i8, setprio around MFMA.
// LDS tiles are 16 rows x 64B (1KB), XOR-swizzled at 16B-granule level:
//   phys_chunk = chunk ^ ((row>>1)&3)
// applied to BOTH the pre-swizzled global staging source and the ds_read addr.
// ---------------------------------------------------------------------------
__global__ __launch_bounds__(512, 2) void gemm_i8_kernel(
    const signed char* __restrict__ A, const signed char* __restrict__ B,
    const float* __restrict__ sA, const float* __restrict__ sB,
    const float* __restrict__ bias, float* __restrict__ C,
    int M, int N, int K)
{
    __shared__ __attribute__((aligned(16))) signed char Ls[3 * 32768]; // 96 KiB

    const int tid = threadIdx.x;
    const int lane = tid & 63, wid = tid >> 6;
    const int wm = wid >> 2, wn = wid & 3;      // 2 x 4 waves

    // XCD-aware bijective blockIdx swizzle
    const int nwg = gridDim.x;
    const int xcd = blockIdx.x & 7, loc = blockIdx.x >> 3;
    const int qq = nwg >> 3, rr = nwg & 7;
    const int wg = (xcd < rr ? xcd * (qq + 1) : rr * (qq + 1) + (xcd - rr) * qq) + loc;

    const int nbn = N >> 8;
    const int m0 = (wg / nbn) << 8;
    const int n0 = (wg % nbn) << 8;

    // ---- staging (wave wid owns A-tiles {2w,2w+1}, B-tiles {2w,2w+1}) ----
    // lane -> tile row lane>>2, PHYSICAL chunk lane&3 holds LOGICAL chunk
    // (lane&3)^((row>>1)&3); (row>>1)&3 == (lane>>3)&3.
    const int srow = lane >> 2;
    const int scol = (((lane & 3) ^ ((lane >> 3) & 3)) << 4);
    const signed char* gA0 = A + (size_t)(m0 + wid * 32 + srow) * K + scol;
    const signed char* gA1 = gA0 + (size_t)16 * K;
    const signed char* gB0 = B + (size_t)(n0 + wid * 32 + srow) * K + scol;
    const signed char* gB1 = gB0 + (size_t)16 * K;
    const int dA0 = wid << 11, dA1 = (wid << 11) + 1024;
    const int dB0 = 16384 + (wid << 11), dB1 = 16384 + (wid << 11) + 1024;

#define STAGE_A(soff, col)                                                         \
    do {                                                                           \
        __builtin_amdgcn_global_load_lds((G_AS1*)(gA0 + (col)),                    \
                                         (L_AS3*)(Ls + (soff) + dA0), 16, 0, 0);   \
        __builtin_amdgcn_global_load_lds((G_AS1*)(gA1 + (col)),                    \
                                         (L_AS3*)(Ls + (soff) + dA1), 16, 0, 0);   \
    } while (0)
#define STAGE_B(soff, col)                                                         \
    do {                                                                           \
        __builtin_amdgcn_global_load_lds((G_AS1*)(gB0 + (col)),                    \
                                         (L_AS3*)(Ls + (soff) + dB0), 16, 0, 0);   \
        __builtin_amdgcn_global_load_lds((G_AS1*)(gB1 + (col)),                    \
                                         (L_AS3*)(Ls + (soff) + dB1), 16, 0, 0);   \
    } while (0)

    // ---- fragment read addressing (swizzled, conflict-free) ----
    // lane wants tile (row r=lane&15, chunk c=lane>>4) -> phys c^((r>>1)&3)
    const unsigned lsb = (unsigned)(unsigned long long)(lds_cp)Ls;
    const unsigned rd = ((unsigned)(lane & 15) << 6) |
                        ((((lane >> 4) ^ ((lane >> 1) & 3)) & 3u) << 4);
    const unsigned aoff = lsb + (wm << 13) + rd;          // + fm*1024
    const unsigned boff = lsb + 16384 + (wn << 12) + rd;  // + fn*1024

    v4i acc[8][4];
    const v4i vz = {0, 0, 0, 0};
#pragma unroll
    for (int i = 0; i < 8; ++i)
#pragma unroll
        for (int j = 0; j < 4; ++j) acc[i][j] = vz;

    const int NT = K >> 6;   // 64 K-tiles

    // prologue: tile0 -> buf0, tile1 -> buf1 (issue order: oldest first)
    STAGE_A(0, 0);      STAGE_B(0, 0);
    STAGE_A(32768, 64); STAGE_B(32768, 64);

    unsigned ro = 0, so = 65536;
    for (int t = 0; t < NT; ++t) {
        int kt2 = (t << 6) + 128;                 // stage col for tile t+2
        if (kt2 > K - 64) kt2 = K - 64;           // clamped dummy re-stage at tail

        asm volatile("s_waitcnt vmcnt(4)" ::: "memory");  // tile t landed
        __builtin_amdgcn_s_barrier();

        const unsigned tA = ro + aoff, tB = ro + boff;
        v4i a[8], b[4];

        // ---- phase 0: read A0-3 + B0-3, stage A(t+2), MFMA fm 0..3 ----
        DSR(a[0], tA, 0);    DSR(a[1], tA, 1024);
        DSR(a[2], tA, 2048); DSR(a[3], tA, 3072);
        DSR(b[0], tB, 0);    DSR(b[1], tB, 1024);
        DSR(b[2], tB, 2048); DSR(b[3], tB, 3072);
        STAGE_A(so, kt2);
        asm volatile("s_waitcnt lgkmcnt(0)" ::: "memory");
        __builtin_amdgcn_sched_barrier(0);
        __builtin_amdgcn_s_setprio(1);
#pragma unroll
        for (int fm = 0; fm < 4; ++fm)
#pragma unroll
            for (int fn = 0; fn < 4; ++fn)
                acc[fm][fn] = __builtin_amdgcn_mfma_i32_16x16x64_i8(
                    a[fm], b[fn], acc[fm][fn], 0, 0, 0);
        __builtin_amdgcn_s_setprio(0);
        __builtin_amdgcn_s_barrier();

        // ---- phase 1: read A4-7, stage B(t+2), MFMA fm 4..7 ----
        DSR(a[4], tA, 4096); DSR(a[5], tA, 5120);
        DSR(a[6], tA, 6144); DSR(a[7], tA, 7168);
        STAGE_B(so, kt2);
        asm volatile("s_waitcnt lgkmcnt(0)" ::: "memory");
        __builtin_amdgcn_sched_barrier(0);
        __builtin_amdgcn_s_setprio(1);
#pragma unroll
        for (int fm = 4; fm < 8; ++fm)
#pragma unroll
            for (int fn = 0; fn < 4; ++fn)
                acc[fm][fn] = __builtin_amdgcn_mfma_i32_16x16x64_i8(
                    a[fm], b[fn], acc[fm][fn], 0, 0, 0);
        __builtin_amdgcn_s_setprio(0);

        // rotate ring (next iter's top barrier closes this K-tile)
        ro += 32768u; if (ro == 98304u) ro = 0;
        so += 32768u; if (so == 98304u) so = 0;
    }
#undef STAGE_A
#undef STAGE_B

    // ---- epilogue: C/D layout col=lane&15, row=(lane>>4)*4+reg ----
    const int l15 = lane & 15, r4 = (lane >> 4) << 2;
#pragma unroll
    for (int fm = 0; fm < 8; ++fm) {
        const int rowb = m0 + (wm << 7) + (fm << 4) + r4;
        const float4 s4 = *(const float4*)(sA + rowb);
        const float sa[4] = {s4.x, s4.y, s4.z, s4.w};
#pragma unroll
        for (int fn = 0; fn < 4; ++fn) {
            const int col = n0 + (wn << 6) + (fn << 4) + l15;
            const float sb = sB[col];
            const float bv = bias[col];
#pragma unroll
            for (int r = 0; r < 4; ++r)
                C[(size_t)(rowb + r) * N + col] =
                    (float)acc[fm][fn][r] * (sa[r] * sb) + bv;
        }
    }
}

// ---------------------------------------------------------------------------
extern "C" void kernel_launch(void* const* d_in, const int* in_sizes, int n_in,
                              void* d_out, int out_size, void* d_ws, size_t ws_size,
                              hipStream_t stream) {
    const float* x    = (const float*)d_in[0];   // [M][K] fp32
    const float* w    = (const float*)d_in[1];   // [N][K] fp32
    const float* bias = (const float*)d_in[2];   // [N]
    float* out = (float*)d_out;

    const int N = in_sizes[2];            // 4096
    const int K = in_sizes[1] / N;        // 4096
    const int M = in_sizes[0] / K;        // 8192

    signed char* qx = (signed char*)d_ws;
    signed char* qw = qx + (size_t)M * K;
    float* sx = (float*)(qw + (size_t)N * K);
    float* sw = sx + M;

    quant_rows_kernel<<<M / 4, 256, 0, stream>>>(x, qx, sx, K);
    quant_rows_kernel<<<N / 4, 256, 0, stream>>>(w, qw, sw, K);

    dim3 grid((M / 256) * (N / 256));     // 512 blocks
    gemm_i8_kernel<<<grid, 512, 0, stream>>>(qx, qw, sx, sw, bias, out, M, N, K);
}

// Round 4
// 394.209 us; speedup vs baseline: 1.3689x; 1.0056x over previous
//
#include <hip/hip_runtime.h>

typedef int v4i __attribute__((ext_vector_type(4)));

#define G_AS1 const __attribute__((address_space(1))) unsigned int
#define L_AS3 __attribute__((address_space(3))) unsigned int
typedef __attribute__((address_space(3))) signed char* lds_cp;

// inline-asm ds_read_b128 with literal offset
#define DSR(d, a, OFF) \
    asm volatile("ds_read_b128 %0, %1 offset:" #OFF : "=v"(d) : "v"(a))

// ---------------------------------------------------------------------------
// Per-row symmetric int8 fake-quant, one wave per row (4 rows / block).
// scale = max(|row|)/127 (IEEE div, clamp 1e-8); q = clip(rintf(v/scale)).
// ---------------------------------------------------------------------------
__global__ __launch_bounds__(256) void quant_rows_kernel(
    const float* __restrict__ in, signed char* __restrict__ q,
    float* __restrict__ scale, int ncols /*==4096*/)
{
    const int wid  = threadIdx.x >> 6;
    const int lane = threadIdx.x & 63;
    const int row  = (blockIdx.x << 2) + wid;

    const float4* inr = (const float4*)(in + (size_t)row * ncols);

    float4 v[16];
    float amax = 0.0f;
#pragma unroll
    for (int i = 0; i < 16; ++i) {
        float4 t = inr[lane + (i << 6)];
        v[i] = t;
        amax = fmaxf(amax, fmaxf(fmaxf(fabsf(t.x), fabsf(t.y)),
                                 fmaxf(fabsf(t.z), fabsf(t.w))));
    }
#pragma unroll
    for (int off = 32; off; off >>= 1)
        amax = fmaxf(amax, __shfl_xor(amax, off));

    const float sc = fmaxf(amax / 127.0f, 1e-8f);
    if (lane == 0) scale[row] = sc;

    int* qr = (int*)(q + (size_t)row * ncols);
#pragma unroll
    for (int i = 0; i < 16; ++i) {
        float4 t = v[i];
        int b0 = (int)fminf(fmaxf(rintf(t.x / sc), -127.0f), 127.0f);
        int b1 = (int)fminf(fmaxf(rintf(t.y / sc), -127.0f), 127.0f);
        int b2 = (int)fminf(fmaxf(rintf(t.z / sc), -127.0f), 127.0f);
        int b3 = (int)fminf(fmaxf(rintf(t.w / sc), -127.0f), 127.0f);
        qr[lane + (i << 6)] = (b0 & 255) | ((b1 & 255) << 8) |
                              ((b2 & 255) << 16) | (b3 << 24);
    }
}

// ---------------------------------------------------------------------------
// int8 GEMM, 256x256 tile, BK=64, 8 waves (2Mx4N), wave tile 128x64.
// 3-buffer LDS ring (96KB). Per K-tile: 2 phases of
//   {ds_read frags -> stage issue -> s_barrier -> lgkmcnt(0) -> 16 MFMA}
// (reads issued BEFORE the barrier so their latency hides under the barrier
//  wait + previous phase's draining MFMAs — m201 phase ordering), then one
// counted vmcnt(4) + barrier closing the K-tile (never vmcnt(0) in-loop).
// LDS tiles 16 rows x 64B (1KB), XOR-swizzled at 16B granules on BOTH the
// pre-swizzled global staging source and the ds_read address.
// ---------------------------------------------------------------------------
__global__ __launch_bounds__(512, 2) void gemm_i8_kernel(
    const signed char* __restrict__ A, const signed char* __restrict__ B,
    const float* __restrict__ sA, const float* __restrict__ sB,
    const float* __restrict__ bias, float* __restrict__ C,
    int M, int N, int K)
{
    __shared__ __attribute__((aligned(16))) signed char Ls[3 * 32768]; // 96 KiB

    const int tid = threadIdx.x;
    const int lane = tid & 63, wid = tid >> 6;
    const int wm = wid >> 2, wn = wid & 3;      // 2 x 4 waves

    // XCD-aware bijective blockIdx swizzle
    const int nwg = gridDim.x;
    const int xcd = blockIdx.x & 7, loc = blockIdx.x >> 3;
    const int qq = nwg >> 3, rr = nwg & 7;
    const int wg = (xcd < rr ? xcd * (qq + 1) : rr * (qq + 1) + (xcd - rr) * qq) + loc;

    const int nbn = N >> 8;
    const int m0 = (wg / nbn) << 8;
    const int n0 = (wg % nbn) << 8;

    // ---- staging (wave wid owns A-tiles {2w,2w+1}, B-tiles {2w,2w+1}) ----
    const int srow = lane >> 2;
    const int scol = (((lane & 3) ^ ((lane >> 3) & 3)) << 4);
    const signed char* gA0 = A + (size_t)(m0 + wid * 32 + srow) * K + scol;
    const signed char* gA1 = gA0 + (size_t)16 * K;
    const signed char* gB0 = B + (size_t)(n0 + wid * 32 + srow) * K + scol;
    const signed char* gB1 = gB0 + (size_t)16 * K;
    const int dA0 = wid << 11, dA1 = (wid << 11) + 1024;
    const int dB0 = 16384 + (wid << 11), dB1 = 16384 + (wid << 11) + 1024;

#define STAGE_A(soff, col)                                                         \
    do {                                                                           \
        __builtin_amdgcn_global_load_lds((G_AS1*)(gA0 + (col)),                    \
                                         (L_AS3*)(Ls + (soff) + dA0), 16, 0, 0);   \
        __builtin_amdgcn_global_load_lds((G_AS1*)(gA1 + (col)),                    \
                                         (L_AS3*)(Ls + (soff) + dA1), 16, 0, 0);   \
    } while (0)
#define STAGE_B(soff, col)                                                         \
    do {                                                                           \
        __builtin_amdgcn_global_load_lds((G_AS1*)(gB0 + (col)),                    \
                                         (L_AS3*)(Ls + (soff) + dB0), 16, 0, 0);   \
        __builtin_amdgcn_global_load_lds((G_AS1*)(gB1 + (col)),                    \
                                         (L_AS3*)(Ls + (soff) + dB1), 16, 0, 0);   \
    } while (0)

    // ---- fragment read addressing (swizzled, conflict-free) ----
    const unsigned lsb = (unsigned)(unsigned long long)(lds_cp)Ls;
    const unsigned rd = ((unsigned)(lane & 15) << 6) |
                        ((((lane >> 4) ^ ((lane >> 1) & 3)) & 3u) << 4);
    const unsigned aoff = lsb + (wm << 13) + rd;          // + fm*1024
    const unsigned boff = lsb + 16384 + (wn << 12) + rd;  // + fn*1024

    v4i acc[8][4];
    const v4i vz = {0, 0, 0, 0};
#pragma unroll
    for (int i = 0; i < 8; ++i)
#pragma unroll
        for (int j = 0; j < 4; ++j) acc[i][j] = vz;

    const int NT = K >> 6;   // 64 K-tiles

    // prologue: tile0 -> buf0, tile1 -> buf1
    STAGE_A(0, 0);      STAGE_B(0, 0);
    STAGE_A(32768, 64); STAGE_B(32768, 64);
    asm volatile("s_waitcnt vmcnt(4)" ::: "memory");  // tile 0 landed
    __builtin_amdgcn_s_barrier();

    unsigned ro = 0, so = 65536;
    for (int t = 0; t < NT; ++t) {
        int kt2 = (t << 6) + 128;                 // stage col for tile t+2
        if (kt2 > K - 64) kt2 = K - 64;           // clamped dummy re-stage at tail

        const unsigned tA = ro + aoff, tB = ro + boff;
        v4i a[8], b[4];

        // ---- phase 0: reads+stage BEFORE barrier, then MFMA fm 0..3 ----
        DSR(a[0], tA, 0);    DSR(a[1], tA, 1024);
        DSR(a[2], tA, 2048); DSR(a[3], tA, 3072);
        DSR(b[0], tB, 0);    DSR(b[1], tB, 1024);
        DSR(b[2], tB, 2048); DSR(b[3], tB, 3072);
        STAGE_A(so, kt2);
        __builtin_amdgcn_s_barrier();
        asm volatile("s_waitcnt lgkmcnt(0)" ::: "memory");
        __builtin_amdgcn_sched_barrier(0);
        __builtin_amdgcn_s_setprio(1);
#pragma unroll
        for (int fm = 0; fm < 4; ++fm)
#pragma unroll
            for (int fn = 0; fn < 4; ++fn)
                acc[fm][fn] = __builtin_amdgcn_mfma_i32_16x16x64_i8(
                    a[fm], b[fn], acc[fm][fn], 0, 0, 0);
        __builtin_amdgcn_s_setprio(0);

        // ---- phase 1: reads+stage BEFORE barrier, then MFMA fm 4..7 ----
        DSR(a[4], tA, 4096); DSR(a[5], tA, 5120);
        DSR(a[6], tA, 6144); DSR(a[7], tA, 7168);
        STAGE_B(so, kt2);
        __builtin_amdgcn_s_barrier();
        asm volatile("s_waitcnt lgkmcnt(0)" ::: "memory");
        __builtin_amdgcn_sched_barrier(0);
        __builtin_amdgcn_s_setprio(1);
#pragma unroll
        for (int fm = 4; fm < 8; ++fm)
#pragma unroll
            for (int fn = 0; fn < 4; ++fn)
                acc[fm][fn] = __builtin_amdgcn_mfma_i32_16x16x64_i8(
                    a[fm], b[fn], acc[fm][fn], 0, 0, 0);
        __builtin_amdgcn_s_setprio(0);

        // ---- close K-tile: tile t+1 must be fully landed for next iter ----
        asm volatile("s_waitcnt vmcnt(4)" ::: "memory");
        __builtin_amdgcn_s_barrier();

        ro += 32768u; if (ro == 98304u) ro = 0;
        so += 32768u; if (so == 98304u) so = 0;
    }
#undef STAGE_A
#undef STAGE_B

    // ---- epilogue: C/D layout col=lane&15, row=(lane>>4)*4+reg ----
    const int l15 = lane & 15, r4 = (lane >> 4) << 2;
#pragma unroll
    for (int fm = 0; fm < 8; ++fm) {
        const int rowb = m0 + (wm << 7) + (fm << 4) + r4;
        const float4 s4 = *(const float4*)(sA + rowb);
        const float sa[4] = {s4.x, s4.y, s4.z, s4.w};
#pragma unroll
        for (int fn = 0; fn < 4; ++fn) {
            const int col = n0 + (wn << 6) + (fn << 4) + l15;
            const float sb = sB[col];
            const float bv = bias[col];
#pragma unroll
            for (int r = 0; r < 4; ++r)
                C[(size_t)(rowb + r) * N + col] =
                    (float)acc[fm][fn][r] * (sa[r] * sb) + bv;
        }
    }
}

// ---------------------------------------------------------------------------
extern "C" void kernel_launch(void* const* d_in, const int* in_sizes, int n_in,
                              void* d_out, int out_size, void* d_ws, size_t ws_size,
                              hipStream_t stream) {
    const float* x    = (const float*)d_in[0];   // [M][K] fp32
    const float* w    = (const float*)d_in[1];   // [N][K] fp32
    const float* bias = (const float*)d_in[2];   // [N]
    float* out = (float*)d_out;

    const int N = in_sizes[2];            // 4096
    const int K = in_sizes[1] / N;        // 4096
    const int M = in_sizes[0] / K;        // 8192

    signed char* qx = (signed char*)d_ws;
    signed char* qw = qx + (size_t)M * K;
    float* sx = (float*)(qw + (size_t)N * K);
    float* sw = sx + M;

    quant_rows_kernel<<<M / 4, 256, 0, stream>>>(x, qx, sx, K);
    quant_rows_kernel<<<N / 4, 256, 0, stream>>>(w, qw, sw, K);

    dim3 grid((M / 256) * (N / 256));     // 512 blocks
    gemm_i8_kernel<<<grid, 512, 0, stream>>>(qx, qw, sx, sw, bias, out, M, N, K);
}